// Round 2
// baseline (1900.908 us; speedup 1.0000x reference)
//
#include <hip/hip_runtime.h>

#define KCW 1024   // num codewords
#define DIM 64     // embedding dim

// ---------------------------------------------------------------------------
// Pre-kernel: cnorm[k] = sum_d codebook[k][d]^2   (1024 floats into d_ws)
// ---------------------------------------------------------------------------
__global__ void __launch_bounds__(256) vq_cnorm_kernel(const float* __restrict__ cb,
                                                       float* __restrict__ cnorm) {
    int k = blockIdx.x * blockDim.x + threadIdx.x;
    if (k < KCW) {
        const float4* c4 = (const float4*)(cb + (size_t)k * DIM);
        float s0 = 0.f, s1 = 0.f, s2 = 0.f, s3 = 0.f;
#pragma unroll
        for (int j = 0; j < DIM / 4; j += 4) {
            float4 a = c4[j + 0];
            float4 b = c4[j + 1];
            float4 c = c4[j + 2];
            float4 d = c4[j + 3];
            s0 += a.x * a.x + a.y * a.y + a.z * a.z + a.w * a.w;
            s1 += b.x * b.x + b.y * b.y + b.z * b.z + b.w * b.w;
            s2 += c.x * c.x + c.y * c.y + c.z * c.z + c.w * c.w;
            s3 += d.x * d.x + d.y * d.y + d.z * d.z + d.w * d.w;
        }
        cnorm[k] = (s0 + s1) + (s2 + s3);
    }
}

// 16-FMA x 4 accumulator dot-product fragment: dot(x_row, cw) over 16 float4.
__device__ __forceinline__ float dot64(const float4* __restrict__ xv,
                                       const float4* __restrict__ c) {
    float a0 = 0.f, a1 = 0.f, a2 = 0.f, a3 = 0.f;
#pragma unroll
    for (int j = 0; j < 16; j += 4) {
        float4 ca = c[j + 0];
        float4 cb = c[j + 1];
        float4 cc = c[j + 2];
        float4 cd = c[j + 3];
        float4 xa = xv[j + 0];
        float4 xb = xv[j + 1];
        float4 xc = xv[j + 2];
        float4 xd = xv[j + 3];
        a0 = fmaf(xa.x, ca.x, a0);
        a0 = fmaf(xa.y, ca.y, a0);
        a0 = fmaf(xa.z, ca.z, a0);
        a0 = fmaf(xa.w, ca.w, a0);
        a1 = fmaf(xb.x, cb.x, a1);
        a1 = fmaf(xb.y, cb.y, a1);
        a1 = fmaf(xb.z, cb.z, a1);
        a1 = fmaf(xb.w, cb.w, a1);
        a2 = fmaf(xc.x, cc.x, a2);
        a2 = fmaf(xc.y, cc.y, a2);
        a2 = fmaf(xc.z, cc.z, a2);
        a2 = fmaf(xc.w, cc.w, a2);
        a3 = fmaf(xd.x, cd.x, a3);
        a3 = fmaf(xd.y, cd.y, a3);
        a3 = fmaf(xd.z, cd.z, a3);
        a3 = fmaf(xd.w, cd.w, a3);
    }
    return (a0 + a1) + (a2 + a3);
}

// ---------------------------------------------------------------------------
// Main kernel: one thread per row, x row register-resident, codebook loads
// double-buffered (cA/cB) so codeword k+1's loads overlap codeword k's FMAs.
// __launch_bounds__(256,1): grid caps us at 2 waves/SIMD anyway, so let the
// allocator use up to ~256 VGPRs instead of demoting x to per-iter reloads
// (R1: VGPR=44 -> x reloaded 1024x -> 950 cyc/codeword vs 128 floor).
// ---------------------------------------------------------------------------
__global__ void __launch_bounds__(256, 1) vq_main_kernel(const float* __restrict__ x,
                                                         const float* __restrict__ cb,
                                                         const float* __restrict__ cnorm,
                                                         float* __restrict__ out_discrete,
                                                         float* __restrict__ out_quant) {
    const int tid = threadIdx.x;
    const int row = blockIdx.x * 256 + tid;

    // x row into registers (16 x float4 = 64 VGPRs), kept live across k-loop.
    float4 xv[16];
    {
        const float4* xr = (const float4*)(x + (size_t)row * DIM);
#pragma unroll
        for (int j = 0; j < 16; ++j) xv[j] = xr[j];
    }

    const float4* cb4 = (const float4*)cb;

    float4 cA[16], cB[16];
#pragma unroll
    for (int j = 0; j < 16; ++j) cA[j] = cb4[j];  // preload codeword 0

    float best = 3.4e38f;
    int bestIdx = 0;

    for (int k = 0; k < KCW; k += 2) {
        // prefetch codeword k+1 while computing k
#pragma unroll
        for (int j = 0; j < 16; ++j) cB[j] = cb4[((k + 1) << 4) + j];

        float score0 = fmaf(-2.f, dot64(xv, cA), cnorm[k]);
        if (score0 < best) {
            best = score0;
            bestIdx = k;
        }

        // prefetch codeword k+2 while computing k+1
        if (k + 2 < KCW) {
#pragma unroll
            for (int j = 0; j < 16; ++j) cA[j] = cb4[((k + 2) << 4) + j];
        }

        float score1 = fmaf(-2.f, dot64(xv, cB), cnorm[k + 1]);
        if (score1 < best) {
            best = score1;
            bestIdx = k + 1;
        }
    }

    __shared__ int sIdx[256];
    sIdx[tid] = bestIdx;
    __syncthreads();

    // ---- quantized: rows [blockIdx*256, +256), 256*16 float4, coalesced ----
    {
        float4* q4 = (float4*)(out_quant + (size_t)blockIdx.x * 256 * DIM);
#pragma unroll
        for (int i = 0; i < 16; ++i) {
            int chunk = i * 256 + tid;
            int rl = chunk >> 4;   // local row (16 float4 per row)
            int j = chunk & 15;    // float4 index within row
            int idx = sIdx[rl];
            const float4* src = (const float4*)cb + (idx << 4);
            q4[chunk] = src[j];
        }
    }

    // ---- one-hot: 256 rows x 1024 floats, fully coalesced float4 stores ----
    {
        float4* o4 = (float4*)(out_discrete + (size_t)blockIdx.x * 256 * KCW);
        const int col = tid * 4;
        for (int it = 0; it < 256; ++it) {
            int idx = sIdx[it];  // block-uniform per iteration
            float4 v;
            v.x = (col + 0 == idx) ? 1.f : 0.f;
            v.y = (col + 1 == idx) ? 1.f : 0.f;
            v.z = (col + 2 == idx) ? 1.f : 0.f;
            v.w = (col + 3 == idx) ? 1.f : 0.f;
            o4[(size_t)it * 256 + tid] = v;
        }
    }
}

// ---------------------------------------------------------------------------
extern "C" void kernel_launch(void* const* d_in, const int* in_sizes, int n_in,
                              void* d_out, int out_size, void* d_ws, size_t ws_size,
                              hipStream_t stream) {
    const float* x = (const float*)d_in[0];
    const float* cb = (const float*)d_in[1];
    float* cnorm = (float*)d_ws;  // 1024 floats of scratch

    const int n = in_sizes[0];        // 8388608
    const int rows = n / DIM;         // 131072

    float* out_discrete = (float*)d_out;
    float* out_quant = (float*)d_out + (size_t)rows * KCW;

    vq_cnorm_kernel<<<(KCW + 255) / 256, 256, 0, stream>>>(cb, cnorm);
    vq_main_kernel<<<rows / 256, 256, 0, stream>>>(x, cb, cnorm, out_discrete, out_quant);
}

// Round 3
// 1215.245 us; speedup vs baseline: 1.5642x; 1.5642x over previous
//
#include <hip/hip_runtime.h>

#define KCW 1024   // num codewords
#define DIM 64     // embedding dim

// ---------------------------------------------------------------------------
// Pre-kernel: cnorm[k] = sum_d codebook[k][d]^2   (1024 floats into d_ws)
// ---------------------------------------------------------------------------
__global__ void __launch_bounds__(256) vq_cnorm_kernel(const float* __restrict__ cb,
                                                       float* __restrict__ cnorm) {
    int k = blockIdx.x * blockDim.x + threadIdx.x;
    if (k < KCW) {
        const float4* c4 = (const float4*)(cb + (size_t)k * DIM);
        float s0 = 0.f, s1 = 0.f, s2 = 0.f, s3 = 0.f;
#pragma unroll
        for (int j = 0; j < DIM / 4; j += 4) {
            float4 a = c4[j + 0];
            float4 b = c4[j + 1];
            float4 c = c4[j + 2];
            float4 d = c4[j + 3];
            s0 += a.x * a.x + a.y * a.y + a.z * a.z + a.w * a.w;
            s1 += b.x * b.x + b.y * b.y + b.z * b.z + b.w * b.w;
            s2 += c.x * c.x + c.y * c.y + c.z * c.z + c.w * c.w;
            s3 += d.x * d.x + d.y * d.y + d.z * d.z + d.w * d.w;
        }
        cnorm[k] = (s0 + s1) + (s2 + s3);
    }
}

// 4 fmaf into one accumulator — same association as R1's passing kernel.
#define FMA4(acc, xa, ca)            \
    acc = fmaf(xa.x, ca.x, acc);     \
    acc = fmaf(xa.y, ca.y, acc);     \
    acc = fmaf(xa.z, ca.z, acc);     \
    acc = fmaf(xa.w, ca.w, acc);

// ---------------------------------------------------------------------------
// Main kernel: one thread per row. NO float4 arrays anywhere — R1/R2 showed
// the compiler demotes float4 arrays to scratch (VGPR_Count=44, FETCH 19 GB
// of scratch thrash). All operands are named registers.
// ---------------------------------------------------------------------------
__global__ void __launch_bounds__(256, 1) vq_main_kernel(const float* __restrict__ x,
                                                         const float* __restrict__ cb,
                                                         const float* __restrict__ cnorm,
                                                         float* __restrict__ out_discrete,
                                                         float* __restrict__ out_quant) {
    const int tid = threadIdx.x;
    const int row = blockIdx.x * 256 + tid;

    // x row in 16 named float4 (64 VGPRs), live across the whole k-loop.
    const float4* xr = (const float4*)(x + (size_t)row * DIM);
    float4 x0 = xr[0], x1 = xr[1], x2 = xr[2], x3 = xr[3];
    float4 x4 = xr[4], x5 = xr[5], x6 = xr[6], x7 = xr[7];
    float4 x8 = xr[8], x9 = xr[9], x10 = xr[10], x11 = xr[11];
    float4 x12 = xr[12], x13 = xr[13], x14 = xr[14], x15 = xr[15];

    const float4* cb4 = (const float4*)cb;

    float best = 3.4e38f;
    int bestIdx = 0;

#pragma unroll 2
    for (int k = 0; k < KCW; ++k) {
        const float4* c = cb4 + (k << 4);
        float4 c0 = c[0], c1 = c[1], c2 = c[2], c3 = c[3];
        float4 c4v = c[4], c5 = c[5], c6 = c[6], c7 = c[7];
        float4 c8 = c[8], c9 = c[9], c10 = c[10], c11 = c[11];
        float4 c12 = c[12], c13 = c[13], c14 = c[14], c15 = c[15];

        float a0 = 0.f, a1 = 0.f, a2 = 0.f, a3 = 0.f;
        FMA4(a0, x0, c0)
        FMA4(a1, x1, c1)
        FMA4(a2, x2, c2)
        FMA4(a3, x3, c3)
        FMA4(a0, x4, c4v)
        FMA4(a1, x5, c5)
        FMA4(a2, x6, c6)
        FMA4(a3, x7, c7)
        FMA4(a0, x8, c8)
        FMA4(a1, x9, c9)
        FMA4(a2, x10, c10)
        FMA4(a3, x11, c11)
        FMA4(a0, x12, c12)
        FMA4(a1, x13, c13)
        FMA4(a2, x14, c14)
        FMA4(a3, x15, c15)

        float dot = (a0 + a1) + (a2 + a3);
        float score = fmaf(-2.f, dot, cnorm[k]);
        // strict < keeps earliest index on ties, matching np.argmin
        if (score < best) {
            best = score;
            bestIdx = k;
        }
    }

    __shared__ int sIdx[256];
    sIdx[tid] = bestIdx;
    __syncthreads();

    // ---- quantized: rows [blockIdx*256, +256), 256*16 float4, coalesced ----
    {
        float4* q4 = (float4*)(out_quant + (size_t)blockIdx.x * 256 * DIM);
#pragma unroll
        for (int i = 0; i < 16; ++i) {
            int chunk = i * 256 + tid;
            int rl = chunk >> 4;   // local row (16 float4 per row)
            int j = chunk & 15;    // float4 index within row
            int idx = sIdx[rl];
            const float4* src = (const float4*)cb + (idx << 4);
            q4[chunk] = src[j];
        }
    }

    // ---- one-hot: 256 rows x 1024 floats, fully coalesced float4 stores ----
    {
        float4* o4 = (float4*)(out_discrete + (size_t)blockIdx.x * 256 * KCW);
        const int col = tid * 4;
        for (int it = 0; it < 256; ++it) {
            int idx = sIdx[it];  // block-uniform per iteration
            float4 v;
            v.x = (col + 0 == idx) ? 1.f : 0.f;
            v.y = (col + 1 == idx) ? 1.f : 0.f;
            v.z = (col + 2 == idx) ? 1.f : 0.f;
            v.w = (col + 3 == idx) ? 1.f : 0.f;
            o4[(size_t)it * 256 + tid] = v;
        }
    }
}

// ---------------------------------------------------------------------------
extern "C" void kernel_launch(void* const* d_in, const int* in_sizes, int n_in,
                              void* d_out, int out_size, void* d_ws, size_t ws_size,
                              hipStream_t stream) {
    const float* x = (const float*)d_in[0];
    const float* cb = (const float*)d_in[1];
    float* cnorm = (float*)d_ws;  // 1024 floats of scratch

    const int n = in_sizes[0];        // 8388608
    const int rows = n / DIM;         // 131072

    float* out_discrete = (float*)d_out;
    float* out_quant = (float*)d_out + (size_t)rows * KCW;

    vq_cnorm_kernel<<<(KCW + 255) / 256, 256, 0, stream>>>(cb, cnorm);
    vq_main_kernel<<<rows / 256, 256, 0, stream>>>(x, cb, cnorm, out_discrete, out_quant);
}

// Round 4
// 1102.030 us; speedup vs baseline: 1.7249x; 1.1027x over previous
//
#include <hip/hip_runtime.h>

#define KCW 1024     // num codewords
#define DIM 64       // embedding dim
#define TILE_CW 256  // codewords per LDS tile: 256 * 64 * 4 B = 64 KB

// ---------------------------------------------------------------------------
// Pre-kernel: cnorm[k] = sum_d codebook[k][d]^2   (1024 floats into d_ws)
// ---------------------------------------------------------------------------
__global__ void __launch_bounds__(256) vq_cnorm_kernel(const float* __restrict__ cb,
                                                       float* __restrict__ cnorm) {
    int k = blockIdx.x * blockDim.x + threadIdx.x;
    if (k < KCW) {
        const float4* c4 = (const float4*)(cb + (size_t)k * DIM);
        float s0 = 0.f, s1 = 0.f, s2 = 0.f, s3 = 0.f;
#pragma unroll
        for (int j = 0; j < DIM / 4; j += 4) {
            float4 a = c4[j + 0];
            float4 b = c4[j + 1];
            float4 c = c4[j + 2];
            float4 d = c4[j + 3];
            s0 += a.x * a.x + a.y * a.y + a.z * a.z + a.w * a.w;
            s1 += b.x * b.x + b.y * b.y + b.z * b.z + b.w * b.w;
            s2 += c.x * c.x + c.y * c.y + c.z * c.z + c.w * c.w;
            s3 += d.x * d.x + d.y * d.y + d.z * d.z + d.w * d.w;
        }
        cnorm[k] = (s0 + s1) + (s2 + s3);
    }
}

#define FMA4(acc, xa, ca)            \
    acc = fmaf(xa.x, ca.x, acc);     \
    acc = fmaf(xa.y, ca.y, acc);     \
    acc = fmaf(xa.z, ca.z, acc);     \
    acc = fmaf(xa.w, ca.w, acc);

// Pin a float4 quartet into VGPRs: asm outputs cannot be re-materialized
// from memory, which defeats the compiler's reload-x-from-global habit
// (R1-R3: VGPR_Count=44, 18.5 GB of HBM fetch from x reloads).
#define PIN4(a, b, c, d)                                                   \
    asm volatile("" : "+v"(a.x), "+v"(a.y), "+v"(a.z), "+v"(a.w),          \
                      "+v"(b.x), "+v"(b.y), "+v"(b.z), "+v"(b.w),          \
                      "+v"(c.x), "+v"(c.y), "+v"(c.z), "+v"(c.w),          \
                      "+v"(d.x), "+v"(d.y), "+v"(d.z), "+v"(d.w));

// async global -> LDS, 16 B per lane (lds dst must be wave-uniform base +
// lane*16 — our layout is exactly lane-contiguous, no padding)
__device__ __forceinline__ void gload_lds16(const float4* g, float4* l) {
    __builtin_amdgcn_global_load_lds(
        (const __attribute__((address_space(1))) void*)g,
        (__attribute__((address_space(3))) void*)l, 16, 0, 0);
}

// ---------------------------------------------------------------------------
// Main kernel: one thread per row. x row pinned in 64 VGPRs; codebook
// streamed through LDS in 64 KB tiles and read back as ds_read_b128
// broadcasts (all lanes same address -> conflict-free).
// ---------------------------------------------------------------------------
__global__ void __launch_bounds__(256, 2) vq_main_kernel(const float* __restrict__ x,
                                                         const float* __restrict__ cb,
                                                         const float* __restrict__ cnorm,
                                                         float* __restrict__ out_discrete,
                                                         float* __restrict__ out_quant) {
    __shared__ float4 sCb[TILE_CW * 16];  // 64 KB codeword tile
    __shared__ float sCn[TILE_CW];        // 1 KB cnorm tile
    __shared__ int sIdx[256];

    const int tid = threadIdx.x;
    const int row = blockIdx.x * 256 + tid;

    // x row in 16 named float4 (64 VGPRs), pinned live across the k-loop.
    const float4* xr = (const float4*)(x + (size_t)row * DIM);
    float4 x0 = xr[0], x1 = xr[1], x2 = xr[2], x3 = xr[3];
    float4 x4 = xr[4], x5 = xr[5], x6 = xr[6], x7 = xr[7];
    float4 x8 = xr[8], x9 = xr[9], x10 = xr[10], x11 = xr[11];
    float4 x12 = xr[12], x13 = xr[13], x14 = xr[14], x15 = xr[15];
    PIN4(x0, x1, x2, x3)
    PIN4(x4, x5, x6, x7)
    PIN4(x8, x9, x10, x11)
    PIN4(x12, x13, x14, x15)

    float best = 3.4e38f;
    int bestIdx = 0;

    for (int t = 0; t < KCW / TILE_CW; ++t) {
        // ---- stage tile t: 4096 float4, 16 per thread, async to LDS ----
        const float4* cbt = (const float4*)cb + (size_t)t * TILE_CW * 16;
#pragma unroll
        for (int i = 0; i < 16; ++i) {
            gload_lds16(cbt + i * 256 + tid, &sCb[i * 256 + tid]);
        }
        sCn[tid] = cnorm[t * TILE_CW + tid];
        __syncthreads();  // drains vmcnt + lgkmcnt

        // ---- 256 codewords from LDS (broadcast reads) ----
        for (int kk = 0; kk < TILE_CW; ++kk) {
            const float4* c = &sCb[kk * 16];
            float4 c0 = c[0], c1 = c[1], c2 = c[2], c3 = c[3];
            float4 c4v = c[4], c5 = c[5], c6 = c[6], c7 = c[7];
            float4 c8 = c[8], c9 = c[9], c10 = c[10], c11 = c[11];
            float4 c12 = c[12], c13 = c[13], c14 = c[14], c15 = c[15];

            float a0 = 0.f, a1 = 0.f, a2 = 0.f, a3 = 0.f;
            FMA4(a0, x0, c0)
            FMA4(a1, x1, c1)
            FMA4(a2, x2, c2)
            FMA4(a3, x3, c3)
            FMA4(a0, x4, c4v)
            FMA4(a1, x5, c5)
            FMA4(a2, x6, c6)
            FMA4(a3, x7, c7)
            FMA4(a0, x8, c8)
            FMA4(a1, x9, c9)
            FMA4(a2, x10, c10)
            FMA4(a3, x11, c11)
            FMA4(a0, x12, c12)
            FMA4(a1, x13, c13)
            FMA4(a2, x14, c14)
            FMA4(a3, x15, c15)

            float dot = (a0 + a1) + (a2 + a3);
            float score = fmaf(-2.f, dot, sCn[kk]);
            // strict < keeps earliest index on ties, matching np.argmin
            if (score < best) {
                best = score;
                bestIdx = t * TILE_CW + kk;
            }
        }
        __syncthreads();  // before overwriting the tile
    }

    sIdx[tid] = bestIdx;
    __syncthreads();

    // ---- quantized: rows [blockIdx*256, +256), 256*16 float4, coalesced ----
    {
        float4* q4 = (float4*)(out_quant + (size_t)blockIdx.x * 256 * DIM);
#pragma unroll
        for (int i = 0; i < 16; ++i) {
            int chunk = i * 256 + tid;
            int rl = chunk >> 4;   // local row (16 float4 per row)
            int j = chunk & 15;    // float4 index within row
            int idx = sIdx[rl];
            const float4* src = (const float4*)cb + (idx << 4);
            q4[chunk] = src[j];
        }
    }

    // ---- one-hot: 256 rows x 1024 floats, fully coalesced float4 stores ----
    {
        float4* o4 = (float4*)(out_discrete + (size_t)blockIdx.x * 256 * KCW);
        const int col = tid * 4;
        for (int it = 0; it < 256; ++it) {
            int idx = sIdx[it];  // block-uniform per iteration
            float4 v;
            v.x = (col + 0 == idx) ? 1.f : 0.f;
            v.y = (col + 1 == idx) ? 1.f : 0.f;
            v.z = (col + 2 == idx) ? 1.f : 0.f;
            v.w = (col + 3 == idx) ? 1.f : 0.f;
            o4[(size_t)it * 256 + tid] = v;
        }
    }
}

// ---------------------------------------------------------------------------
extern "C" void kernel_launch(void* const* d_in, const int* in_sizes, int n_in,
                              void* d_out, int out_size, void* d_ws, size_t ws_size,
                              hipStream_t stream) {
    const float* x = (const float*)d_in[0];
    const float* cb = (const float*)d_in[1];
    float* cnorm = (float*)d_ws;  // 1024 floats of scratch

    const int n = in_sizes[0];        // 8388608
    const int rows = n / DIM;         // 131072

    float* out_discrete = (float*)d_out;
    float* out_quant = (float*)d_out + (size_t)rows * KCW;

    vq_cnorm_kernel<<<(KCW + 255) / 256, 256, 0, stream>>>(cb, cnorm);
    vq_main_kernel<<<rows / 256, 256, 0, stream>>>(x, cb, cnorm, out_discrete, out_quant);
}